// Round 10
// baseline (174.930 us; speedup 1.0000x reference)
//
#include <hip/hip_runtime.h>

#define N_NODES 100000
#define N_EDGES 800000
#define EHALF (N_EDGES / 2)
#define H 128
#define MAX_Z 1000
#define N_GRAPHS 500
#define ELL_CAP 32
#define NB 391                   // node blocks: ceil(100000/256)
#define TB 125                   // table-convert blocks: 32000 float4 / 256
#define MAXC1 33008              // count1 <= 1000*(1+32), padded to 16
#define NC_ROWS 1008             // 1000 center rows padded to 16
#define CTR0 0                   // list0 counter (own cache line)
#define CTR1 64                  // list1 counter (separate cache line)
#define LA_GRID 2080             // grid-stride blocks for layerA
#define LB_GRID 1040             // grid-stride blocks for layerB
#define N0_GRID 2064             // grid-stride blocks for k_n0

typedef __attribute__((ext_vector_type(8))) short bf16x8;
typedef __attribute__((ext_vector_type(4))) float f32x4;

__device__ __forceinline__ unsigned short f2bf(float f) {
    union { float f; unsigned u; } x; x.f = f;
    unsigned r = x.u + 0x7fffu + ((x.u >> 16) & 1u);   // RTNE
    return (unsigned short)(r >> 16);
}
__device__ __forceinline__ float bf2f(unsigned short u) {
    return __uint_as_float((unsigned)u << 16);
}
__device__ __forceinline__ int clampid(int p) {       // poison (0xAA..) is negative
    return (p < 0 || p >= N_NODES) ? 0 : p;
}

// ---- setup: zero flags/ctrs + pack W (bf16 B-frag) + convert table to bf16
__global__ void k_setup(int* fill, int* f0, int* f1, int* ctrs,
                        const float* W0, const float* W1, const float* W2,
                        unsigned short* Wp, const float* ztab,
                        unsigned short* tabb) {
    int b = blockIdx.x;
    if (b < NB) {
        int i = b * 256 + threadIdx.x;
        if (i < N_NODES) { fill[i] = 0; f0[i] = 0; f1[i] = 0; }
        if (i < 128) ctrs[i] = 0;
    } else if (b < NB + 24) {
        int bb = b - NB;                       // 0..23
        int wi = bb >> 3;
        const float* W = (wi == 0) ? W0 : (wi == 1) ? W1 : W2;
        int t = (bb & 7) * 256 + threadIdx.x;  // 0..2047
        int lane = t & 63, kt = (t >> 6) & 3, c = t >> 8;
        int quad = lane >> 4, n = c * 16 + (lane & 15);
        unsigned short o[8];
#pragma unroll
        for (int j = 0; j < 8; j++)
            o[j] = f2bf(W[(kt * 32 + quad * 8 + j) * H + n]);
        ushort4 lo = { o[0], o[1], o[2], o[3] }, hi = { o[4], o[5], o[6], o[7] };
        unsigned short* dst = Wp + (size_t)wi * 16384 + (size_t)t * 8;
        *(ushort4*)(dst)     = lo;
        *(ushort4*)(dst + 4) = hi;
    } else {
        int i = (b - NB - 24) * 256 + threadIdx.x;   // float4 index
        if (i < MAX_Z * H / 4) {
            float4 v = *(const float4*)(ztab + (size_t)i * 4);
            ushort4 o = { f2bf(v.x), f2bf(v.y), f2bf(v.z), f2bf(v.w) };
            *(ushort4*)(tabb + (size_t)i * 4) = o;
        }
    }
}

// ---- single edge scan: 2 edges/thread, loads hoisted above branches ------
__global__ void k_edge(const int* __restrict__ src, const int* __restrict__ dst,
                       const int* __restrict__ mask, int* fill, int* ell) {
    int e = blockIdx.x * 256 + threadIdx.x;
    if (e >= EHALF) return;
    int m0 = mask[e], m1 = mask[e + EHALF];        // all six loads independent,
    int d0 = dst[e],  d1 = dst[e + EHALF];         // issued before any branch
    int s0 = src[e],  s1 = src[e + EHALF];
    if (m0) {
        int p = atomicAdd(&fill[d0], 1);
        if (p < ELL_CAP) ell[(size_t)d0 * ELL_CAP + p] = s0;
    }
    if (m1) {
        int p = atomicAdd(&fill[d1], 1);
        if (p < ELL_CAP) ell[(size_t)d1 * ELL_CAP + p] = s1;
    }
}

// ---- N1 = centers U in(centers). Block-aggregated list allocation. -------
__global__ void k_n1(const int* fill, const int* ell, int* f1, int* f0,
                     int* list1, int* list0, int* ctrs) {
    __shared__ int wtot[4];
    __shared__ int bbase0, bbase1;
    int tid = threadIdx.x, lane = tid & 63, wv = tid >> 6;
    int c = blockIdx.x * 4 + wv;
    int s = -1;
    if (c < 2 * N_GRAPHS) {
        int v = (c >> 1) * 200 + (c & 1);
        int n = fill[v]; if (n > ELL_CAP) n = ELL_CAP;
        s = (lane < n) ? ell[(size_t)v * ELL_CAP + lane] : ((lane == n) ? v : -1);
    }
    bool need = false;
    if (s >= 0 && atomicExch(&f1[s], 1) == 0) {
        f0[s] = 1;                 // winner is unique; plain store suffices
        need = true;
    }
    unsigned long long b = __ballot(need);
    int total = __popcll(b);
    int pre = __popcll(b & ((1ull << lane) - 1ull));
    if (lane == 0) wtot[wv] = total;
    __syncthreads();
    if (tid == 0) {
        int bt = wtot[0] + wtot[1] + wtot[2] + wtot[3];
        if (bt) {
            bbase1 = atomicAdd(&ctrs[CTR1], bt);
            bbase0 = atomicAdd(&ctrs[CTR0], bt);
        }
    }
    __syncthreads();
    if (need) {
        int off = pre;
        for (int w2 = 0; w2 < 4; w2++) if (w2 < wv) off += wtot[w2];
        list1[bbase1 + off] = s;
        list0[bbase0 + off] = s;
    }
}

// ---- N0 = N1 U in(N1). Grid-stride; block-aggregated allocation. ---------
__global__ void k_n0(const int* fill, const int* ell, const int* list1,
                     int* f0, int* list0, int* ctrs) {
    __shared__ int wtot[4];
    __shared__ int bbase;
    int tid = threadIdx.x, lane = tid & 63, wv = tid >> 6;
    int cnt1 = ctrs[CTR1];         // read-only line during this kernel
    for (int base = blockIdx.x * 4; base < cnt1; base += N0_GRID * 4) {
        int i = base + wv;
        bool need = false;
        int s = 0;
        if (i < cnt1) {
            int v = list1[i];
            int n = fill[v]; if (n > ELL_CAP) n = ELL_CAP;
            if (lane < n) {
                s = ell[(size_t)v * ELL_CAP + lane];
                need = (atomicExch(&f0[s], 1) == 0);
            }
        }
        unsigned long long b = __ballot(need);
        int total = __popcll(b);
        int pre = __popcll(b & ((1ull << lane) - 1ull));
        if (lane == 0) wtot[wv] = total;
        __syncthreads();
        if (tid == 0) {
            int bt = wtot[0] + wtot[1] + wtot[2] + wtot[3];
            if (bt) bbase = atomicAdd(&ctrs[CTR0], bt);
        }
        __syncthreads();
        if (need) {
            int off = pre;
            for (int w2 = 0; w2 < 4; w2++) if (w2 < wv) off += wtot[w2];
            list0[bbase + off] = s;
        }
        __syncthreads();           // protect wtot/bbase before next iteration
    }
}

// ---- fused layer A: agg from bf16 table + GEMM + bias + ReLU + scatter ---
// 512 threads = 8 waves; 2 rows/wave; ELL row loaded unguarded (clamped)
__global__ __launch_bounds__(512) void k_layerA(const int* __restrict__ z,
                                                const unsigned short* __restrict__ tabb,
                                                const int* __restrict__ ell,
                                                const int* __restrict__ fill,
                                                const int* __restrict__ list,
                                                const int* countp,
                                                const unsigned short* __restrict__ Wp,
                                                const float* __restrict__ bias,
                                                unsigned short* xb) {
    __shared__ unsigned short yt[16][136];
    int count = *countp;
    int tid = threadIdx.x, lane = tid & 63, wv = tid >> 6;   // wv 0..7
    int l2 = lane * 2;
    int m = lane & 15, quad = lane >> 4;

    for (int t = blockIdx.x; t * 16 < count; t += LA_GRID) {
        for (int q = 0; q < 2; q++) {
            int r = t * 16 + wv * 2 + q;
            float ax = 0.f, ay = 0.f;
            if (r < count) {
                int v = list[r];
                // issue all preamble loads in parallel (chain: list -> {...})
                int ntrue = fill[v];
                int px = 0;
                if (lane < ELL_CAP) px = ell[(size_t)v * ELL_CAP + lane];
                px = clampid(px);            // poison-safe; lanes >= n unused
                int zx = z[px];
                int fx = fill[px];
                int zv = z[v];
                int n = ntrue > ELL_CAP ? ELL_CAP : ntrue;
                float dv = rsqrtf(1.0f + (float)ntrue);
                float pc = (lane < n) ? rsqrtf(1.0f + (float)fx) * dv : 0.f;
                float sc = dv * dv;
                ushort2 xs = *(const ushort2*)(tabb + (size_t)zv * H + l2);
                ax = sc * bf2f(xs.x); ay = sc * bf2f(xs.y);
                int k = 0;
                for (; k + 3 < n; k += 4) {
                    int z0 = __shfl(zx, k),   z1 = __shfl(zx, k + 1);
                    int z2 = __shfl(zx, k + 2), z3 = __shfl(zx, k + 3);
                    float c0 = __shfl(pc, k),   c1 = __shfl(pc, k + 1);
                    float c2 = __shfl(pc, k + 2), c3 = __shfl(pc, k + 3);
                    ushort2 m0 = *(const ushort2*)(tabb + (size_t)z0 * H + l2);
                    ushort2 m1 = *(const ushort2*)(tabb + (size_t)z1 * H + l2);
                    ushort2 m2 = *(const ushort2*)(tabb + (size_t)z2 * H + l2);
                    ushort2 m3 = *(const ushort2*)(tabb + (size_t)z3 * H + l2);
                    ax += c0 * bf2f(m0.x) + c1 * bf2f(m1.x) + c2 * bf2f(m2.x) + c3 * bf2f(m3.x);
                    ay += c0 * bf2f(m0.y) + c1 * bf2f(m1.y) + c2 * bf2f(m2.y) + c3 * bf2f(m3.y);
                }
                for (; k < n; k++) {
                    int zz = __shfl(zx, k); float c = __shfl(pc, k);
                    ushort2 m0 = *(const ushort2*)(tabb + (size_t)zz * H + l2);
                    ax += c * bf2f(m0.x); ay += c * bf2f(m0.y);
                }
            }
            ushort2 o; o.x = f2bf(ax); o.y = f2bf(ay);
            *(ushort2*)&yt[wv * 2 + q][l2] = o;
        }
        __syncthreads();

        // GEMM: wave wv owns column tile c = wv (8 waves, 8 tiles)
        bf16x8 a0 = *(const bf16x8*)&yt[m][quad * 8];
        bf16x8 a1 = *(const bf16x8*)&yt[m][32 + quad * 8];
        bf16x8 a2 = *(const bf16x8*)&yt[m][64 + quad * 8];
        bf16x8 a3 = *(const bf16x8*)&yt[m][96 + quad * 8];
        const unsigned short* bp = Wp + ((size_t)(wv * 4) * 64 + lane) * 8;
        bf16x8 b0 = *(const bf16x8*)(bp);
        bf16x8 b1 = *(const bf16x8*)(bp + 64 * 8);
        bf16x8 b2 = *(const bf16x8*)(bp + 128 * 8);
        bf16x8 b3 = *(const bf16x8*)(bp + 192 * 8);
        f32x4 a = (f32x4){0.f, 0.f, 0.f, 0.f};
        a = __builtin_amdgcn_mfma_f32_16x16x32_bf16(a0, b0, a, 0, 0, 0);
        a = __builtin_amdgcn_mfma_f32_16x16x32_bf16(a1, b1, a, 0, 0, 0);
        a = __builtin_amdgcn_mfma_f32_16x16x32_bf16(a2, b2, a, 0, 0, 0);
        a = __builtin_amdgcn_mfma_f32_16x16x32_bf16(a3, b3, a, 0, 0, 0);

        int r0 = t * 16 + quad * 4;
        int col = wv * 16 + m;
        float bv = bias[col];
#pragma unroll
        for (int i = 0; i < 4; i++) {
            int r = r0 + i;
            if (r < count)
                xb[(size_t)list[r] * H + col] = f2bf(fmaxf(a[i] + bv, 0.f));
        }
        __syncthreads();   // protect yt before next stride iteration
    }
}

// ---- fused layer B: agg from bf16 xin + GEMM + bias + ReLU -> xout -------
__global__ __launch_bounds__(512) void k_layerB(const unsigned short* __restrict__ xin,
                                                const int* __restrict__ ell,
                                                const int* __restrict__ fill,
                                                const int* __restrict__ list,
                                                const int* countp,
                                                const unsigned short* __restrict__ Wp,
                                                const float* __restrict__ bias,
                                                unsigned short* xout) {
    __shared__ unsigned short yt[16][136];
    int count = *countp;
    int tid = threadIdx.x, lane = tid & 63, wv = tid >> 6;   // wv 0..7
    int l2 = lane * 2;
    int m = lane & 15, quad = lane >> 4;

    for (int t = blockIdx.x; t * 16 < count; t += LB_GRID) {
        for (int q = 0; q < 2; q++) {
            int r = t * 16 + wv * 2 + q;
            float ax = 0.f, ay = 0.f;
            if (r < count) {
                int v = list[r];
                int ntrue = fill[v];
                int px = 0;
                if (lane < ELL_CAP) px = ell[(size_t)v * ELL_CAP + lane];
                px = clampid(px);
                int fx = fill[px];
                ushort2 xs = *(const ushort2*)(xin + (size_t)v * H + l2);
                int n = ntrue > ELL_CAP ? ELL_CAP : ntrue;
                float dv = rsqrtf(1.0f + (float)ntrue);
                float pc = (lane < n) ? rsqrtf(1.0f + (float)fx) * dv : 0.f;
                float sc = dv * dv;
                ax = sc * bf2f(xs.x); ay = sc * bf2f(xs.y);
                int k = 0;
                for (; k + 3 < n; k += 4) {
                    int s0 = __shfl(px, k),   s1 = __shfl(px, k + 1);
                    int s2 = __shfl(px, k + 2), s3 = __shfl(px, k + 3);
                    float c0 = __shfl(pc, k),   c1 = __shfl(pc, k + 1);
                    float c2 = __shfl(pc, k + 2), c3 = __shfl(pc, k + 3);
                    ushort2 m0 = *(const ushort2*)(xin + (size_t)s0 * H + l2);
                    ushort2 m1 = *(const ushort2*)(xin + (size_t)s1 * H + l2);
                    ushort2 m2 = *(const ushort2*)(xin + (size_t)s2 * H + l2);
                    ushort2 m3 = *(const ushort2*)(xin + (size_t)s3 * H + l2);
                    ax += c0 * bf2f(m0.x) + c1 * bf2f(m1.x) + c2 * bf2f(m2.x) + c3 * bf2f(m3.x);
                    ay += c0 * bf2f(m0.y) + c1 * bf2f(m1.y) + c2 * bf2f(m2.y) + c3 * bf2f(m3.y);
                }
                for (; k < n; k++) {
                    int s = __shfl(px, k); float c = __shfl(pc, k);
                    ushort2 m0 = *(const ushort2*)(xin + (size_t)s * H + l2);
                    ax += c * bf2f(m0.x); ay += c * bf2f(m0.y);
                }
            }
            ushort2 o; o.x = f2bf(ax); o.y = f2bf(ay);
            *(ushort2*)&yt[wv * 2 + q][l2] = o;
        }
        __syncthreads();

        bf16x8 a0 = *(const bf16x8*)&yt[m][quad * 8];
        bf16x8 a1 = *(const bf16x8*)&yt[m][32 + quad * 8];
        bf16x8 a2 = *(const bf16x8*)&yt[m][64 + quad * 8];
        bf16x8 a3 = *(const bf16x8*)&yt[m][96 + quad * 8];
        const unsigned short* bp = Wp + ((size_t)(wv * 4) * 64 + lane) * 8;
        bf16x8 b0 = *(const bf16x8*)(bp);
        bf16x8 b1 = *(const bf16x8*)(bp + 64 * 8);
        bf16x8 b2 = *(const bf16x8*)(bp + 128 * 8);
        bf16x8 b3 = *(const bf16x8*)(bp + 192 * 8);
        f32x4 a = (f32x4){0.f, 0.f, 0.f, 0.f};
        a = __builtin_amdgcn_mfma_f32_16x16x32_bf16(a0, b0, a, 0, 0, 0);
        a = __builtin_amdgcn_mfma_f32_16x16x32_bf16(a1, b1, a, 0, 0, 0);
        a = __builtin_amdgcn_mfma_f32_16x16x32_bf16(a2, b2, a, 0, 0, 0);
        a = __builtin_amdgcn_mfma_f32_16x16x32_bf16(a3, b3, a, 0, 0, 0);

        int r0 = t * 16 + quad * 4;
        int col = wv * 16 + m;
        float bv = bias[col];
#pragma unroll
        for (int i = 0; i < 4; i++) {
            int r = r0 + i;
            if (r < count)
                xout[(size_t)list[r] * H + col] = f2bf(fmaxf(a[i] + bv, 0.f));
        }
        __syncthreads();   // protect yt before next stride iteration
    }
}

// ---- fused layer 2 + head: agg at centers + GEMM + hadamard + MLP --------
__global__ __launch_bounds__(256) void k_layer2(const unsigned short* __restrict__ xin,
                                                const int* __restrict__ ell,
                                                const int* __restrict__ fill,
                                                const unsigned short* __restrict__ Wp,
                                                const float* b2,
                                                const float* l1w, const float* l1b,
                                                const float* l2w, const float* l2b,
                                                float* out) {
    __shared__ unsigned short yt[16][136];
    __shared__ float ct[16][132];
    int t = blockIdx.x;                       // 0..62
    int tid = threadIdx.x, lane = tid & 63, wv = tid >> 6;
    int l2 = lane * 2;

    for (int q = 0; q < 4; q++) {
        int idx = t * 16 + wv * 4 + q;
        float ax = 0.f, ay = 0.f;
        if (idx < 2 * N_GRAPHS) {
            int v = (idx >> 1) * 200 + (idx & 1);
            int ntrue = fill[v];
            int px = 0;
            if (lane < ELL_CAP) px = ell[(size_t)v * ELL_CAP + lane];
            px = clampid(px);
            int fx = fill[px];
            ushort2 xs = *(const ushort2*)(xin + (size_t)v * H + l2);
            int n = ntrue > ELL_CAP ? ELL_CAP : ntrue;
            float dv = rsqrtf(1.0f + (float)ntrue);
            float pc = (lane < n) ? rsqrtf(1.0f + (float)fx) * dv : 0.f;
            float sc = dv * dv;
            ax = sc * bf2f(xs.x); ay = sc * bf2f(xs.y);
            int k = 0;
            for (; k + 3 < n; k += 4) {
                int s0 = __shfl(px, k),   s1 = __shfl(px, k + 1);
                int s2 = __shfl(px, k + 2), s3 = __shfl(px, k + 3);
                float c0 = __shfl(pc, k),   c1 = __shfl(pc, k + 1);
                float c2 = __shfl(pc, k + 2), c3 = __shfl(pc, k + 3);
                ushort2 m0 = *(const ushort2*)(xin + (size_t)s0 * H + l2);
                ushort2 m1 = *(const ushort2*)(xin + (size_t)s1 * H + l2);
                ushort2 m2 = *(const ushort2*)(xin + (size_t)s2 * H + l2);
                ushort2 m3 = *(const ushort2*)(xin + (size_t)s3 * H + l2);
                ax += c0 * bf2f(m0.x) + c1 * bf2f(m1.x) + c2 * bf2f(m2.x) + c3 * bf2f(m3.x);
                ay += c0 * bf2f(m0.y) + c1 * bf2f(m1.y) + c2 * bf2f(m2.y) + c3 * bf2f(m3.y);
            }
            for (; k < n; k++) {
                int s = __shfl(px, k); float c = __shfl(pc, k);
                ushort2 m0 = *(const ushort2*)(xin + (size_t)s * H + l2);
                ax += c * bf2f(m0.x); ay += c * bf2f(m0.y);
            }
        }
        ushort2 o; o.x = f2bf(ax); o.y = f2bf(ay);
        *(ushort2*)&yt[wv * 4 + q][l2] = o;
    }
    __syncthreads();

    int m = lane & 15, quad = lane >> 4;
    bf16x8 a0 = *(const bf16x8*)&yt[m][quad * 8];
    bf16x8 a1 = *(const bf16x8*)&yt[m][32 + quad * 8];
    bf16x8 a2 = *(const bf16x8*)&yt[m][64 + quad * 8];
    bf16x8 a3 = *(const bf16x8*)&yt[m][96 + quad * 8];

#pragma unroll
    for (int c2 = 0; c2 < 2; c2++) {
        int c = wv * 2 + c2;
        const unsigned short* bp = Wp + ((size_t)(c * 4) * 64 + lane) * 8;
        bf16x8 b0 = *(const bf16x8*)(bp);
        bf16x8 b1 = *(const bf16x8*)(bp + 64 * 8);
        bf16x8 bb = *(const bf16x8*)(bp + 128 * 8);
        bf16x8 b3 = *(const bf16x8*)(bp + 192 * 8);
        f32x4 a = (f32x4){0.f, 0.f, 0.f, 0.f};
        a = __builtin_amdgcn_mfma_f32_16x16x32_bf16(a0, b0, a, 0, 0, 0);
        a = __builtin_amdgcn_mfma_f32_16x16x32_bf16(a1, b1, a, 0, 0, 0);
        a = __builtin_amdgcn_mfma_f32_16x16x32_bf16(a2, bb, a, 0, 0, 0);
        a = __builtin_amdgcn_mfma_f32_16x16x32_bf16(a3, b3, a, 0, 0, 0);
        int col = c * 16 + m;
        float bv = b2[col];
#pragma unroll
        for (int i = 0; i < 4; i++)
            ct[quad * 4 + i][col] = a[i] + bv;
    }
    __syncthreads();

    // head: 8 graphs per block; 32 threads per graph, 4 output feats each
    int gl = tid >> 5, jq = tid & 31, j4 = jq * 4;
    int g = t * 8 + gl;
    float4 h = *(const float4*)(l1b + j4);
    const float* r0 = &ct[2 * gl][0];
    const float* r1 = &ct[2 * gl + 1][0];
#pragma unroll 4
    for (int k = 0; k < H; k++) {
        float pk = r0[k] * r1[k];
        float4 wv4 = *(const float4*)(l1w + (size_t)k * H + j4);
        h.x += pk * wv4.x; h.y += pk * wv4.y;
        h.z += pk * wv4.z; h.w += pk * wv4.w;
    }
    float4 l2v = *(const float4*)(l2w + j4);
    float s = fmaxf(h.x, 0.f) * l2v.x + fmaxf(h.y, 0.f) * l2v.y +
              fmaxf(h.z, 0.f) * l2v.z + fmaxf(h.w, 0.f) * l2v.w;
#pragma unroll
    for (int d = 16; d > 0; d >>= 1) s += __shfl_xor(s, d, 32);
    if (jq == 0 && g < N_GRAPHS) out[g] = s + l2b[0];
}

extern "C" void kernel_launch(void* const* d_in, const int* in_sizes, int n_in,
                              void* d_out, int out_size, void* d_ws, size_t ws_size,
                              hipStream_t stream) {
    const int*   z    = (const int*)d_in[0];
    const int*   esrc = (const int*)d_in[1];
    const int*   edst = ((const int*)d_in[1]) + N_EDGES;
    const int*   mask = (const int*)d_in[3];
    const float* ztab = (const float*)d_in[4];
    const float* W0   = (const float*)d_in[5];
    const float* b0   = (const float*)d_in[6];
    const float* W1   = (const float*)d_in[7];
    const float* b1   = (const float*)d_in[8];
    const float* W2   = (const float*)d_in[9];
    const float* b2   = (const float*)d_in[10];
    const float* l1w  = (const float*)d_in[11];
    const float* l1b  = (const float*)d_in[12];
    const float* l2w  = (const float*)d_in[13];
    const float* l2b  = (const float*)d_in[14];
    float* out = (float*)d_out;

    char* w = (char*)d_ws;
    size_t o = 0;
    auto carve = [&](size_t bytes) { char* p = w + o; o = (o + bytes + 255) & ~(size_t)255; return p; };
    unsigned short* xb    = (unsigned short*)carve((size_t)N_NODES * H * 2);  // layer-0 out
    unsigned short* xc    = (unsigned short*)carve((size_t)N_NODES * H * 2);  // layer-1 out
    int*            fill  = (int*)carve((size_t)N_NODES * 4);
    int*            ell   = (int*)carve((size_t)N_NODES * ELL_CAP * 4);
    int*            f0    = (int*)carve((size_t)N_NODES * 4);
    int*            f1    = (int*)carve((size_t)N_NODES * 4);
    int*            list0 = (int*)carve((size_t)N_NODES * 4);
    int*            list1 = (int*)carve((size_t)MAXC1 * 4);
    int*            ctrs  = (int*)carve(512);
    unsigned short* Wp    = (unsigned short*)carve((size_t)3 * 16384 * 2);
    unsigned short* tabb  = (unsigned short*)carve((size_t)MAX_Z * H * 2);

    // setup: init flags/counters + pack weights + bf16 table (one kernel)
    k_setup<<<NB + 24 + TB, 256, 0, stream>>>(fill, f0, f1, ctrs,
                                              W0, W1, W2, Wp, ztab, tabb);
    // single full edge scan: 2 edges/thread, hoisted loads
    k_edge <<<(EHALF + 255) / 256, 256, 0, stream>>>(esrc, edst, mask, fill, ell);
    // frontier expansion via ELL walks; block-aggregated, split-line counters
    k_n1   <<<(2 * N_GRAPHS + 3) / 4, 256, 0, stream>>>(fill, ell, f1, f0, list1, list0, ctrs);
    k_n0   <<<N0_GRID, 256, 0, stream>>>(fill, ell, list1, f0, list0, ctrs);

    // layer 0 (N0 rows) -> xb
    k_layerA<<<LA_GRID, 512, 0, stream>>>(z, tabb, ell, fill, list0,
                                          &ctrs[CTR0], Wp, b0, xb);
    // layer 1 (N1 rows): read xb, write xc (no in-place hazard)
    k_layerB<<<LB_GRID, 512, 0, stream>>>(xb, ell, fill, list1, &ctrs[CTR1],
                                          Wp + 16384, b1, xc);
    // layer 2 + pooling + MLP head (reads xc)
    k_layer2<<<NC_ROWS / 16, 256, 0, stream>>>(xc, ell, fill, Wp + 32768, b2,
                                               l1w, l1b, l2w, l2b, out);
}

// Round 11
// 173.566 us; speedup vs baseline: 1.0079x; 1.0079x over previous
//
#include <hip/hip_runtime.h>

#define N_NODES 100000
#define N_EDGES 800000
#define EHALF (N_EDGES / 2)
#define H 128
#define MAX_Z 1000
#define N_GRAPHS 500
#define ELL_CAP 32
#define NB 391                   // node blocks: ceil(100000/256)
#define TB 125                   // table-convert blocks: 32000 float4 / 256
#define MAXC1 33008              // count1 <= 1000*(1+32), padded to 16
#define NC_ROWS 1008             // 1000 center rows padded to 16
#define CTR0 0                   // list0 counter (own cache line)
#define CTR1 64                  // list1 counter (separate cache line)
#define AG_GRID 6144             // grid-stride blocks for k_agg0
#define LB_GRID 1040             // grid-stride blocks for layerB
#define N0_GRID 2064             // grid-stride blocks for k_n0

typedef __attribute__((ext_vector_type(8))) short bf16x8;
typedef __attribute__((ext_vector_type(4))) float f32x4;

__device__ __forceinline__ unsigned short f2bf(float f) {
    union { float f; unsigned u; } x; x.f = f;
    unsigned r = x.u + 0x7fffu + ((x.u >> 16) & 1u);   // RTNE
    return (unsigned short)(r >> 16);
}
__device__ __forceinline__ float bf2f(unsigned short u) {
    return __uint_as_float((unsigned)u << 16);
}
__device__ __forceinline__ int clampid(int p) {       // poison (0xAA..) is negative
    return (p < 0 || p >= N_NODES) ? 0 : p;
}

// ---- setup: zero flags/ctrs + pack W (bf16 B-frag) + convert table to bf16
__global__ void k_setup(int* fill, int* f0, int* f1, int* ctrs,
                        const float* W0, const float* W1, const float* W2,
                        unsigned short* Wp, const float* ztab,
                        unsigned short* tabb) {
    int b = blockIdx.x;
    if (b < NB) {
        int i = b * 256 + threadIdx.x;
        if (i < N_NODES) { fill[i] = 0; f0[i] = 0; f1[i] = 0; }
        if (i < 128) ctrs[i] = 0;
    } else if (b < NB + 24) {
        int bb = b - NB;                       // 0..23
        int wi = bb >> 3;
        const float* W = (wi == 0) ? W0 : (wi == 1) ? W1 : W2;
        int t = (bb & 7) * 256 + threadIdx.x;  // 0..2047
        int lane = t & 63, kt = (t >> 6) & 3, c = t >> 8;
        int quad = lane >> 4, n = c * 16 + (lane & 15);
        unsigned short o[8];
#pragma unroll
        for (int j = 0; j < 8; j++)
            o[j] = f2bf(W[(kt * 32 + quad * 8 + j) * H + n]);
        ushort4 lo = { o[0], o[1], o[2], o[3] }, hi = { o[4], o[5], o[6], o[7] };
        unsigned short* dst = Wp + (size_t)wi * 16384 + (size_t)t * 8;
        *(ushort4*)(dst)     = lo;
        *(ushort4*)(dst + 4) = hi;
    } else {
        int i = (b - NB - 24) * 256 + threadIdx.x;   // float4 index
        if (i < MAX_Z * H / 4) {
            float4 v = *(const float4*)(ztab + (size_t)i * 4);
            ushort4 o = { f2bf(v.x), f2bf(v.y), f2bf(v.z), f2bf(v.w) };
            *(ushort4*)(tabb + (size_t)i * 4) = o;
        }
    }
}

// ---- T0 = tabb @ W0 (1000x128 bf16 GEMM; layer-0 GEMM hoisted to z-table)
__global__ __launch_bounds__(512) void k_tgemm(const unsigned short* __restrict__ tabb,
                                               const unsigned short* __restrict__ Wp,
                                               unsigned short* T0) {
    int tid = threadIdx.x, lane = tid & 63, wv = tid >> 6;   // wv 0..7
    int m = lane & 15, quad = lane >> 4;
    int t = blockIdx.x;                      // 0..62
    int row = t * 16 + m;
    const unsigned short* ar = tabb + (size_t)(row < MAX_Z ? row : 0) * H + quad * 8;
    bf16x8 a0 = *(const bf16x8*)(ar);
    bf16x8 a1 = *(const bf16x8*)(ar + 32);
    bf16x8 a2 = *(const bf16x8*)(ar + 64);
    bf16x8 a3 = *(const bf16x8*)(ar + 96);
    const unsigned short* bp = Wp + ((size_t)(wv * 4) * 64 + lane) * 8;
    bf16x8 b0 = *(const bf16x8*)(bp);
    bf16x8 b1 = *(const bf16x8*)(bp + 64 * 8);
    bf16x8 b2 = *(const bf16x8*)(bp + 128 * 8);
    bf16x8 b3 = *(const bf16x8*)(bp + 192 * 8);
    f32x4 a = (f32x4){0.f, 0.f, 0.f, 0.f};
    a = __builtin_amdgcn_mfma_f32_16x16x32_bf16(a0, b0, a, 0, 0, 0);
    a = __builtin_amdgcn_mfma_f32_16x16x32_bf16(a1, b1, a, 0, 0, 0);
    a = __builtin_amdgcn_mfma_f32_16x16x32_bf16(a2, b2, a, 0, 0, 0);
    a = __builtin_amdgcn_mfma_f32_16x16x32_bf16(a3, b3, a, 0, 0, 0);
    int r0 = t * 16 + quad * 4;
    int col = wv * 16 + m;
#pragma unroll
    for (int i = 0; i < 4; i++) {
        int r = r0 + i;
        if (r < MAX_Z) T0[(size_t)r * H + col] = f2bf(a[i]);
    }
}

// ---- single edge scan: 2 edges/thread, loads hoisted above branches ------
__global__ void k_edge(const int* __restrict__ src, const int* __restrict__ dst,
                       const int* __restrict__ mask, int* fill, int* ell) {
    int e = blockIdx.x * 256 + threadIdx.x;
    if (e >= EHALF) return;
    int m0 = mask[e], m1 = mask[e + EHALF];
    int d0 = dst[e],  d1 = dst[e + EHALF];
    int s0 = src[e],  s1 = src[e + EHALF];
    if (m0) {
        int p = atomicAdd(&fill[d0], 1);
        if (p < ELL_CAP) ell[(size_t)d0 * ELL_CAP + p] = s0;
    }
    if (m1) {
        int p = atomicAdd(&fill[d1], 1);
        if (p < ELL_CAP) ell[(size_t)d1 * ELL_CAP + p] = s1;
    }
}

// ---- N1 = centers U in(centers). Block-aggregated list allocation. -------
__global__ void k_n1(const int* fill, const int* ell, int* f1, int* f0,
                     int* list1, int* list0, int* ctrs) {
    __shared__ int wtot[4];
    __shared__ int bbase0, bbase1;
    int tid = threadIdx.x, lane = tid & 63, wv = tid >> 6;
    int c = blockIdx.x * 4 + wv;
    int s = -1;
    if (c < 2 * N_GRAPHS) {
        int v = (c >> 1) * 200 + (c & 1);
        int n = fill[v]; if (n > ELL_CAP) n = ELL_CAP;
        s = (lane < n) ? ell[(size_t)v * ELL_CAP + lane] : ((lane == n) ? v : -1);
    }
    bool need = false;
    if (s >= 0 && atomicExch(&f1[s], 1) == 0) {
        f0[s] = 1;                 // winner is unique; plain store suffices
        need = true;
    }
    unsigned long long b = __ballot(need);
    int total = __popcll(b);
    int pre = __popcll(b & ((1ull << lane) - 1ull));
    if (lane == 0) wtot[wv] = total;
    __syncthreads();
    if (tid == 0) {
        int bt = wtot[0] + wtot[1] + wtot[2] + wtot[3];
        if (bt) {
            bbase1 = atomicAdd(&ctrs[CTR1], bt);
            bbase0 = atomicAdd(&ctrs[CTR0], bt);
        }
    }
    __syncthreads();
    if (need) {
        int off = pre;
        for (int w2 = 0; w2 < 4; w2++) if (w2 < wv) off += wtot[w2];
        list1[bbase1 + off] = s;
        list0[bbase0 + off] = s;
    }
}

// ---- N0 = N1 U in(N1). Grid-stride; block-aggregated allocation. ---------
__global__ void k_n0(const int* fill, const int* ell, const int* list1,
                     int* f0, int* list0, int* ctrs) {
    __shared__ int wtot[4];
    __shared__ int bbase;
    int tid = threadIdx.x, lane = tid & 63, wv = tid >> 6;
    int cnt1 = ctrs[CTR1];         // read-only line during this kernel
    for (int base = blockIdx.x * 4; base < cnt1; base += N0_GRID * 4) {
        int i = base + wv;
        bool need = false;
        int s = 0;
        if (i < cnt1) {
            int v = list1[i];
            int n = fill[v]; if (n > ELL_CAP) n = ELL_CAP;
            if (lane < n) {
                s = ell[(size_t)v * ELL_CAP + lane];
                need = (atomicExch(&f0[s], 1) == 0);
            }
        }
        unsigned long long b = __ballot(need);
        int total = __popcll(b);
        int pre = __popcll(b & ((1ull << lane) - 1ull));
        if (lane == 0) wtot[wv] = total;
        __syncthreads();
        if (tid == 0) {
            int bt = wtot[0] + wtot[1] + wtot[2] + wtot[3];
            if (bt) bbase = atomicAdd(&ctrs[CTR0], bt);
        }
        __syncthreads();
        if (need) {
            int off = pre;
            for (int w2 = 0; w2 < 4; w2++) if (w2 < wv) off += wtot[w2];
            list0[bbase + off] = s;
        }
        __syncthreads();           // protect wtot/bbase before next iteration
    }
}

// ---- layer 0: pure aggregation of T0 rows + bias + ReLU -> xb ------------
// out[v] = relu( sc*T0[z[v]] + sum coef*T0[z[s]] + b0 ); one wave per row
__global__ __launch_bounds__(256) void k_agg0(const int* __restrict__ z,
                                              const unsigned short* __restrict__ T0,
                                              const int* __restrict__ ell,
                                              const int* __restrict__ fill,
                                              const int* __restrict__ list,
                                              const int* countp,
                                              const float* __restrict__ bias,
                                              unsigned short* xb) {
    int count = *countp;
    int tid = threadIdx.x, lane = tid & 63, wv = tid >> 6;
    int l2 = lane * 2;
    float2 bv = *(const float2*)(bias + l2);
    for (int i = blockIdx.x * 4 + wv; i < count; i += AG_GRID * 4) {
        int v = list[i];
        int ntrue = fill[v];
        int px = 0;
        if (lane < ELL_CAP) px = ell[(size_t)v * ELL_CAP + lane];
        px = clampid(px);              // poison-safe; lanes >= n unused
        int zx = z[px];
        int fx = fill[px];
        int zv = z[v];
        int n = ntrue > ELL_CAP ? ELL_CAP : ntrue;
        float dv = rsqrtf(1.0f + (float)ntrue);
        float pc = (lane < n) ? rsqrtf(1.0f + (float)fx) * dv : 0.f;
        float sc = dv * dv;
        ushort2 xs = *(const ushort2*)(T0 + (size_t)zv * H + l2);
        float ax = sc * bf2f(xs.x) + bv.x;
        float ay = sc * bf2f(xs.y) + bv.y;
        int k = 0;
        for (; k + 3 < n; k += 4) {
            int z0 = __shfl(zx, k),   z1 = __shfl(zx, k + 1);
            int z2 = __shfl(zx, k + 2), z3 = __shfl(zx, k + 3);
            float c0 = __shfl(pc, k),   c1 = __shfl(pc, k + 1);
            float c2 = __shfl(pc, k + 2), c3 = __shfl(pc, k + 3);
            ushort2 m0 = *(const ushort2*)(T0 + (size_t)z0 * H + l2);
            ushort2 m1 = *(const ushort2*)(T0 + (size_t)z1 * H + l2);
            ushort2 m2 = *(const ushort2*)(T0 + (size_t)z2 * H + l2);
            ushort2 m3 = *(const ushort2*)(T0 + (size_t)z3 * H + l2);
            ax += c0 * bf2f(m0.x) + c1 * bf2f(m1.x) + c2 * bf2f(m2.x) + c3 * bf2f(m3.x);
            ay += c0 * bf2f(m0.y) + c1 * bf2f(m1.y) + c2 * bf2f(m2.y) + c3 * bf2f(m3.y);
        }
        for (; k < n; k++) {
            int zz = __shfl(zx, k); float c = __shfl(pc, k);
            ushort2 m0 = *(const ushort2*)(T0 + (size_t)zz * H + l2);
            ax += c * bf2f(m0.x); ay += c * bf2f(m0.y);
        }
        ushort2 o;
        o.x = f2bf(fmaxf(ax, 0.f));
        o.y = f2bf(fmaxf(ay, 0.f));
        *(ushort2*)(xb + (size_t)v * H + l2) = o;
    }
}

// ---- fused layer B: agg from bf16 xin + GEMM + bias + ReLU -> xout -------
__global__ __launch_bounds__(512) void k_layerB(const unsigned short* __restrict__ xin,
                                                const int* __restrict__ ell,
                                                const int* __restrict__ fill,
                                                const int* __restrict__ list,
                                                const int* countp,
                                                const unsigned short* __restrict__ Wp,
                                                const float* __restrict__ bias,
                                                unsigned short* xout) {
    __shared__ unsigned short yt[16][136];
    int count = *countp;
    int tid = threadIdx.x, lane = tid & 63, wv = tid >> 6;   // wv 0..7
    int l2 = lane * 2;
    int m = lane & 15, quad = lane >> 4;

    for (int t = blockIdx.x; t * 16 < count; t += LB_GRID) {
        for (int q = 0; q < 2; q++) {
            int r = t * 16 + wv * 2 + q;
            float ax = 0.f, ay = 0.f;
            if (r < count) {
                int v = list[r];
                int ntrue = fill[v];
                int px = 0;
                if (lane < ELL_CAP) px = ell[(size_t)v * ELL_CAP + lane];
                px = clampid(px);
                int fx = fill[px];
                ushort2 xs = *(const ushort2*)(xin + (size_t)v * H + l2);
                int n = ntrue > ELL_CAP ? ELL_CAP : ntrue;
                float dv = rsqrtf(1.0f + (float)ntrue);
                float pc = (lane < n) ? rsqrtf(1.0f + (float)fx) * dv : 0.f;
                float sc = dv * dv;
                ax = sc * bf2f(xs.x); ay = sc * bf2f(xs.y);
                int k = 0;
                for (; k + 3 < n; k += 4) {
                    int s0 = __shfl(px, k),   s1 = __shfl(px, k + 1);
                    int s2 = __shfl(px, k + 2), s3 = __shfl(px, k + 3);
                    float c0 = __shfl(pc, k),   c1 = __shfl(pc, k + 1);
                    float c2 = __shfl(pc, k + 2), c3 = __shfl(pc, k + 3);
                    ushort2 m0 = *(const ushort2*)(xin + (size_t)s0 * H + l2);
                    ushort2 m1 = *(const ushort2*)(xin + (size_t)s1 * H + l2);
                    ushort2 m2 = *(const ushort2*)(xin + (size_t)s2 * H + l2);
                    ushort2 m3 = *(const ushort2*)(xin + (size_t)s3 * H + l2);
                    ax += c0 * bf2f(m0.x) + c1 * bf2f(m1.x) + c2 * bf2f(m2.x) + c3 * bf2f(m3.x);
                    ay += c0 * bf2f(m0.y) + c1 * bf2f(m1.y) + c2 * bf2f(m2.y) + c3 * bf2f(m3.y);
                }
                for (; k < n; k++) {
                    int s = __shfl(px, k); float c = __shfl(pc, k);
                    ushort2 m0 = *(const ushort2*)(xin + (size_t)s * H + l2);
                    ax += c * bf2f(m0.x); ay += c * bf2f(m0.y);
                }
            }
            ushort2 o; o.x = f2bf(ax); o.y = f2bf(ay);
            *(ushort2*)&yt[wv * 2 + q][l2] = o;
        }
        __syncthreads();

        bf16x8 a0 = *(const bf16x8*)&yt[m][quad * 8];
        bf16x8 a1 = *(const bf16x8*)&yt[m][32 + quad * 8];
        bf16x8 a2 = *(const bf16x8*)&yt[m][64 + quad * 8];
        bf16x8 a3 = *(const bf16x8*)&yt[m][96 + quad * 8];
        const unsigned short* bp = Wp + ((size_t)(wv * 4) * 64 + lane) * 8;
        bf16x8 b0 = *(const bf16x8*)(bp);
        bf16x8 b1 = *(const bf16x8*)(bp + 64 * 8);
        bf16x8 b2 = *(const bf16x8*)(bp + 128 * 8);
        bf16x8 b3 = *(const bf16x8*)(bp + 192 * 8);
        f32x4 a = (f32x4){0.f, 0.f, 0.f, 0.f};
        a = __builtin_amdgcn_mfma_f32_16x16x32_bf16(a0, b0, a, 0, 0, 0);
        a = __builtin_amdgcn_mfma_f32_16x16x32_bf16(a1, b1, a, 0, 0, 0);
        a = __builtin_amdgcn_mfma_f32_16x16x32_bf16(a2, b2, a, 0, 0, 0);
        a = __builtin_amdgcn_mfma_f32_16x16x32_bf16(a3, b3, a, 0, 0, 0);

        int r0 = t * 16 + quad * 4;
        int col = wv * 16 + m;
        float bv = bias[col];
#pragma unroll
        for (int i = 0; i < 4; i++) {
            int r = r0 + i;
            if (r < count)
                xout[(size_t)list[r] * H + col] = f2bf(fmaxf(a[i] + bv, 0.f));
        }
        __syncthreads();   // protect yt before next stride iteration
    }
}

// ---- fused layer 2 + head: agg at centers + GEMM + hadamard + MLP --------
__global__ __launch_bounds__(256) void k_layer2(const unsigned short* __restrict__ xin,
                                                const int* __restrict__ ell,
                                                const int* __restrict__ fill,
                                                const unsigned short* __restrict__ Wp,
                                                const float* b2,
                                                const float* l1w, const float* l1b,
                                                const float* l2w, const float* l2b,
                                                float* out) {
    __shared__ unsigned short yt[16][136];
    __shared__ float ct[16][132];
    int t = blockIdx.x;                       // 0..62
    int tid = threadIdx.x, lane = tid & 63, wv = tid >> 6;
    int l2 = lane * 2;

    for (int q = 0; q < 4; q++) {
        int idx = t * 16 + wv * 4 + q;
        float ax = 0.f, ay = 0.f;
        if (idx < 2 * N_GRAPHS) {
            int v = (idx >> 1) * 200 + (idx & 1);
            int ntrue = fill[v];
            int px = 0;
            if (lane < ELL_CAP) px = ell[(size_t)v * ELL_CAP + lane];
            px = clampid(px);
            int fx = fill[px];
            ushort2 xs = *(const ushort2*)(xin + (size_t)v * H + l2);
            int n = ntrue > ELL_CAP ? ELL_CAP : ntrue;
            float dv = rsqrtf(1.0f + (float)ntrue);
            float pc = (lane < n) ? rsqrtf(1.0f + (float)fx) * dv : 0.f;
            float sc = dv * dv;
            ax = sc * bf2f(xs.x); ay = sc * bf2f(xs.y);
            int k = 0;
            for (; k + 3 < n; k += 4) {
                int s0 = __shfl(px, k),   s1 = __shfl(px, k + 1);
                int s2 = __shfl(px, k + 2), s3 = __shfl(px, k + 3);
                float c0 = __shfl(pc, k),   c1 = __shfl(pc, k + 1);
                float c2 = __shfl(pc, k + 2), c3 = __shfl(pc, k + 3);
                ushort2 m0 = *(const ushort2*)(xin + (size_t)s0 * H + l2);
                ushort2 m1 = *(const ushort2*)(xin + (size_t)s1 * H + l2);
                ushort2 m2 = *(const ushort2*)(xin + (size_t)s2 * H + l2);
                ushort2 m3 = *(const ushort2*)(xin + (size_t)s3 * H + l2);
                ax += c0 * bf2f(m0.x) + c1 * bf2f(m1.x) + c2 * bf2f(m2.x) + c3 * bf2f(m3.x);
                ay += c0 * bf2f(m0.y) + c1 * bf2f(m1.y) + c2 * bf2f(m2.y) + c3 * bf2f(m3.y);
            }
            for (; k < n; k++) {
                int s = __shfl(px, k); float c = __shfl(pc, k);
                ushort2 m0 = *(const ushort2*)(xin + (size_t)s * H + l2);
                ax += c * bf2f(m0.x); ay += c * bf2f(m0.y);
            }
        }
        ushort2 o; o.x = f2bf(ax); o.y = f2bf(ay);
        *(ushort2*)&yt[wv * 4 + q][l2] = o;
    }
    __syncthreads();

    int m = lane & 15, quad = lane >> 4;
    bf16x8 a0 = *(const bf16x8*)&yt[m][quad * 8];
    bf16x8 a1 = *(const bf16x8*)&yt[m][32 + quad * 8];
    bf16x8 a2 = *(const bf16x8*)&yt[m][64 + quad * 8];
    bf16x8 a3 = *(const bf16x8*)&yt[m][96 + quad * 8];

#pragma unroll
    for (int c2 = 0; c2 < 2; c2++) {
        int c = wv * 2 + c2;
        const unsigned short* bp = Wp + ((size_t)(c * 4) * 64 + lane) * 8;
        bf16x8 b0 = *(const bf16x8*)(bp);
        bf16x8 b1 = *(const bf16x8*)(bp + 64 * 8);
        bf16x8 bb = *(const bf16x8*)(bp + 128 * 8);
        bf16x8 b3 = *(const bf16x8*)(bp + 192 * 8);
        f32x4 a = (f32x4){0.f, 0.f, 0.f, 0.f};
        a = __builtin_amdgcn_mfma_f32_16x16x32_bf16(a0, b0, a, 0, 0, 0);
        a = __builtin_amdgcn_mfma_f32_16x16x32_bf16(a1, b1, a, 0, 0, 0);
        a = __builtin_amdgcn_mfma_f32_16x16x32_bf16(a2, bb, a, 0, 0, 0);
        a = __builtin_amdgcn_mfma_f32_16x16x32_bf16(a3, b3, a, 0, 0, 0);
        int col = c * 16 + m;
        float bv = b2[col];
#pragma unroll
        for (int i = 0; i < 4; i++)
            ct[quad * 4 + i][col] = a[i] + bv;
    }
    __syncthreads();

    // head: 8 graphs per block; 32 threads per graph, 4 output feats each
    int gl = tid >> 5, jq = tid & 31, j4 = jq * 4;
    int g = t * 8 + gl;
    float4 h = *(const float4*)(l1b + j4);
    const float* r0 = &ct[2 * gl][0];
    const float* r1 = &ct[2 * gl + 1][0];
#pragma unroll 4
    for (int k = 0; k < H; k++) {
        float pk = r0[k] * r1[k];
        float4 wv4 = *(const float4*)(l1w + (size_t)k * H + j4);
        h.x += pk * wv4.x; h.y += pk * wv4.y;
        h.z += pk * wv4.z; h.w += pk * wv4.w;
    }
    float4 l2v = *(const float4*)(l2w + j4);
    float s = fmaxf(h.x, 0.f) * l2v.x + fmaxf(h.y, 0.f) * l2v.y +
              fmaxf(h.z, 0.f) * l2v.z + fmaxf(h.w, 0.f) * l2v.w;
#pragma unroll
    for (int d = 16; d > 0; d >>= 1) s += __shfl_xor(s, d, 32);
    if (jq == 0 && g < N_GRAPHS) out[g] = s + l2b[0];
}

extern "C" void kernel_launch(void* const* d_in, const int* in_sizes, int n_in,
                              void* d_out, int out_size, void* d_ws, size_t ws_size,
                              hipStream_t stream) {
    const int*   z    = (const int*)d_in[0];
    const int*   esrc = (const int*)d_in[1];
    const int*   edst = ((const int*)d_in[1]) + N_EDGES;
    const int*   mask = (const int*)d_in[3];
    const float* ztab = (const float*)d_in[4];
    const float* W0   = (const float*)d_in[5];
    const float* b0   = (const float*)d_in[6];
    const float* W1   = (const float*)d_in[7];
    const float* b1   = (const float*)d_in[8];
    const float* W2   = (const float*)d_in[9];
    const float* b2   = (const float*)d_in[10];
    const float* l1w  = (const float*)d_in[11];
    const float* l1b  = (const float*)d_in[12];
    const float* l2w  = (const float*)d_in[13];
    const float* l2b  = (const float*)d_in[14];
    float* out = (float*)d_out;

    char* w = (char*)d_ws;
    size_t o = 0;
    auto carve = [&](size_t bytes) { char* p = w + o; o = (o + bytes + 255) & ~(size_t)255; return p; };
    unsigned short* xb    = (unsigned short*)carve((size_t)N_NODES * H * 2);  // layer-0 out
    unsigned short* xc    = (unsigned short*)carve((size_t)N_NODES * H * 2);  // layer-1 out
    int*            fill  = (int*)carve((size_t)N_NODES * 4);
    int*            ell   = (int*)carve((size_t)N_NODES * ELL_CAP * 4);
    int*            f0    = (int*)carve((size_t)N_NODES * 4);
    int*            f1    = (int*)carve((size_t)N_NODES * 4);
    int*            list0 = (int*)carve((size_t)N_NODES * 4);
    int*            list1 = (int*)carve((size_t)MAXC1 * 4);
    int*            ctrs  = (int*)carve(512);
    unsigned short* Wp    = (unsigned short*)carve((size_t)3 * 16384 * 2);
    unsigned short* tabb  = (unsigned short*)carve((size_t)MAX_Z * H * 2);
    unsigned short* T0    = (unsigned short*)carve((size_t)MAX_Z * H * 2);

    // setup: init flags/counters + pack weights + bf16 table (one kernel)
    k_setup<<<NB + 24 + TB, 256, 0, stream>>>(fill, f0, f1, ctrs,
                                              W0, W1, W2, Wp, ztab, tabb);
    // hoisted layer-0 GEMM on the 1000-entry z-table: T0 = tabb @ W0
    k_tgemm<<<NC_ROWS / 16, 512, 0, stream>>>(tabb, Wp, T0);
    // single full edge scan: 2 edges/thread, hoisted loads
    k_edge <<<(EHALF + 255) / 256, 256, 0, stream>>>(esrc, edst, mask, fill, ell);
    // frontier expansion via ELL walks; block-aggregated, split-line counters
    k_n1   <<<(2 * N_GRAPHS + 3) / 4, 256, 0, stream>>>(fill, ell, f1, f0, list1, list0, ctrs);
    k_n0   <<<N0_GRID, 256, 0, stream>>>(fill, ell, list1, f0, list0, ctrs);

    // layer 0 (N0 rows): pure T0-row aggregation + bias + ReLU -> xb
    k_agg0<<<AG_GRID, 256, 0, stream>>>(z, T0, ell, fill, list0, &ctrs[CTR0],
                                        b0, xb);
    // layer 1 (N1 rows): read xb, write xc (no in-place hazard)
    k_layerB<<<LB_GRID, 512, 0, stream>>>(xb, ell, fill, list1, &ctrs[CTR1],
                                          Wp + 16384, b1, xc);
    // layer 2 + pooling + MLP head (reads xc)
    k_layer2<<<NC_ROWS / 16, 256, 0, stream>>>(xc, ell, fill, Wp + 32768, b2,
                                               l1w, l1b, l2w, l2b, out);
}